// Round 9
// baseline (4999.957 us; speedup 1.0000x reference)
//
#include <hip/hip_runtime.h>
#include <hip/hip_bf16.h>
#include <math.h>

// RITS RNN + late attention. Round 12: REBALANCED 4-SEGMENT SCAN.
//  - r11 post-mortem: removing segments saved only 0.5us/step (15.8 vs 16.3)
//    -> cost is NOT segment count; it's segment C's 768KB b5 stream pulled
//    through the CU's L2 path (~8us) plus ~2us latency floors on thin segs.
//  - gates = [c_c|m]@W_ih^T + h_dec@W_hh^T. The m/h_dec operands (kt 2..11,
//    640KB of b5) are ready at step start (staged in D of t-1). Move that
//    partial GEMM into segment A (parallel with x_h + gamma MFMAs; A-frags
//    reused across all 8 n-tiles), park partials in sh_gates; segment C
//    shrinks to kt 0..1 (c_c, 128KB) and adds on top. Partials go via LDS,
//    not registers, to stay under the 128-VGPR cap (round-5 spill lesson).
//  - Deferred attention kernel + ws guard + fused fallback unchanged (r10).
// ws: f32 ws[0]=xl ws[1]=y ws[2]=tr_sum ws[16..272)=msum; bf16 frags at
// WS_B5/B6/B3/B2/B7; bf16 H[1024][256][256] at WS_H_OFS.

#define BB 1024
#define SS 256
#define NF 64
#define HD 256
#define DAA 350
#define DRR 30
#define RPB 4

#define WS_B5_OFS 4096
#define WS_B5_ELEMS (64 * 12 * 64 * 8)
#define WS_B6_OFS (WS_B5_OFS + WS_B5_ELEMS * 2)
#define WS_B6_ELEMS (22 * 8 * 64 * 8)
#define WS_B3_OFS (WS_B6_OFS + WS_B6_ELEMS * 2)
#define WS_B3_ELEMS (4 * 8 * 64 * 8)
#define WS_B2_OFS (WS_B3_OFS + WS_B3_ELEMS * 2)
#define WS_B2_ELEMS (16 * 2 * 64 * 8)
#define WS_B7_OFS (WS_B2_OFS + WS_B2_ELEMS * 2)
#define WS_B7_ELEMS (2 * 11 * 64 * 8)
#define CW_TOTAL (WS_B5_ELEMS + WS_B6_ELEMS + WS_B3_ELEMS + WS_B2_ELEMS + WS_B7_ELEMS)
#define WS_H_OFS (2 * 1024 * 1024)
#define WS_H_BYTES ((size_t)BB * SS * HD * 2)

typedef __attribute__((ext_vector_type(8))) short bf16x8;
typedef __attribute__((ext_vector_type(4))) float f32x4;

__device__ __forceinline__ float dot4f(float4 a, float4 b) {
  return fmaf(a.x, b.x, fmaf(a.y, b.y, fmaf(a.z, b.z, a.w * b.w)));
}

__device__ __forceinline__ short f2bs(float v) {
  __hip_bfloat16 t = __float2bfloat16(v);
  return *reinterpret_cast<short*>(&t);
}

__global__ __launch_bounds__(256) void convert_weights(
    const float* __restrict__ W_ih, const float* __restrict__ W_hh,
    const float* __restrict__ Ws1_W, const float* __restrict__ hist_W,
    const float* __restrict__ td_h_W, const float* __restrict__ Ws2_W,
    short* __restrict__ b5, short* __restrict__ b6,
    short* __restrict__ b3, short* __restrict__ b2, short* __restrict__ b7)
{
  int idx = blockIdx.x * 256 + threadIdx.x;
  if (idx < WS_B5_ELEMS) {
    int j = idx & 7; int e8 = idx >> 3; int lane = e8 & 63; int tile = e8 >> 6;
    int kt = tile % 12, nt = tile / 12;
    int g = nt * 16 + (lane & 15);
    int k = kt * 32 + (lane >> 4) * 8 + j;  // [c_c(64)|m(64)|h(256)]
    float v = (k < 128) ? W_ih[g * 128 + k] : W_hh[g * 256 + (k - 128)];
    b5[idx] = f2bs(v);
  } else if (idx < WS_B5_ELEMS + WS_B6_ELEMS) {
    int i = idx - WS_B5_ELEMS;
    int j = i & 7; int e8 = i >> 3; int lane = e8 & 63; int tile = e8 >> 6;
    int kt = tile & 7, nt = tile >> 3;
    int a = nt * 16 + (lane & 15);
    int k = kt * 32 + (lane >> 4) * 8 + j;
    float v = (a < DAA) ? Ws1_W[a * 256 + k] : 0.f;
    b6[i] = f2bs(v);
  } else if (idx < WS_B5_ELEMS + WS_B6_ELEMS + WS_B3_ELEMS) {
    int i = idx - WS_B5_ELEMS - WS_B6_ELEMS;
    int j = i & 7; int e8 = i >> 3; int lane = e8 & 63; int tile = e8 >> 6;
    int kt = tile & 7, nt = tile >> 3;
    int n = nt * 16 + (lane & 15);
    int k = kt * 32 + (lane >> 4) * 8 + j;
    b3[i] = f2bs(hist_W[n * 256 + k]);
  } else if (idx < WS_B5_ELEMS + WS_B6_ELEMS + WS_B3_ELEMS + WS_B2_ELEMS) {
    int i = idx - WS_B5_ELEMS - WS_B6_ELEMS - WS_B3_ELEMS;
    int j = i & 7; int e8 = i >> 3; int lane = e8 & 63; int tile = e8 >> 6;
    int kt = tile & 1, nt = tile >> 1;
    int g = nt * 16 + (lane & 15);
    int k = kt * 32 + (lane >> 4) * 8 + j;
    b2[i] = f2bs(td_h_W[g * 64 + k]);
  } else if (idx < CW_TOTAL) {
    int i = idx - WS_B5_ELEMS - WS_B6_ELEMS - WS_B3_ELEMS - WS_B2_ELEMS;
    int j = i & 7; int e8 = i >> 3; int lane = e8 & 63; int tile = e8 >> 6;
    int kt = tile % 11, nt = tile / 11;
    int r = nt * 16 + (lane & 15);
    int k = kt * 32 + (lane >> 4) * 8 + j;
    float v = (r < DRR && k < DAA) ? Ws2_W[r * DAA + k] : 0.f;
    b7[i] = f2bs(v);
  }
}

__global__ __launch_bounds__(256) void prep_kernel(
    const float* __restrict__ masks, const float* __restrict__ is_train,
    float* __restrict__ ws)
{
  __shared__ float red[256];
  const int t = blockIdx.x;
  const int tid = threadIdx.x;
  float s = 0.f;
  for (int idx = tid; idx < BB * NF; idx += 256) {
    int b = idx >> 6, n = idx & 63;
    s += masks[(size_t)b * (SS * NF) + (size_t)t * NF + n];
  }
  red[tid] = s;
  __syncthreads();
  for (int off = 128; off > 0; off >>= 1) {
    if (tid < off) red[tid] += red[tid + off];
    __syncthreads();
  }
  if (tid == 0) ws[16 + t] = red[0] + 1e-5f;
  if (blockIdx.x == 0) {
    __syncthreads();
    float ts = 0.f;
    for (int idx = tid; idx < BB; idx += 256) ts += is_train[idx];
    red[tid] = ts;
    __syncthreads();
    for (int off = 128; off > 0; off >>= 1) {
      if (tid < off) red[tid] += red[tid + off];
      __syncthreads();
    }
    if (tid == 0) { ws[2] = red[0]; ws[0] = 0.f; ws[1] = 0.f; }
  }
}

// ---------------- scan kernel: 4 rebalanced segments per step --------------
__global__ __launch_bounds__(512, 2) void rits_scan(
    const float* __restrict__ values, const float* __restrict__ masks_g,
    const float* __restrict__ deltas,
    const float* __restrict__ td_h_b, const float* __restrict__ td_x_W,
    const float* __restrict__ td_x_b, const float* __restrict__ hist_b,
    const float* __restrict__ feat_W, const float* __restrict__ feat_b,
    const float* __restrict__ comb_W, const float* __restrict__ comb_b,
    const float* __restrict__ b_ih, const float* __restrict__ b_hh,
    float* __restrict__ out, float* __restrict__ ws)
{
  __shared__ __align__(16) short sh_ab[16][392];   // bf16 [c_c|m|h_dec], rows 4+ zero
  __shared__ __align__(16) short sh_db[16][72];    // bf16 d_{t+1}, rows 4+ zero
  __shared__ __align__(16) float sh_x[RPB][NF];
  __shared__ __align__(16) float sh_m[RPB][NF];
  __shared__ __align__(16) float sh_xc[RPB][NF];
  __shared__ __align__(16) float sh_gx[RPB][NF];   // gamma_x(t)
  __shared__ __align__(16) float sh_xh[RPB][NF];
  __shared__ __align__(16) float sh_gam[RPB][HD];  // gamma_h(t+1) f32
  __shared__ __align__(16) float sh_gates[RPB][1024];
  __shared__ float sh_msum;

  const int tid = threadIdx.x;
  const int b0 = blockIdx.x * RPB;
  const int wv = tid >> 6;
  const int lane = tid & 63;
  const int lm = lane & 15;
  const int lq = lane >> 4;
  const int row = tid >> 7;      // LSTM row 0..3
  const int j = tid & 127;
  const int jA = j, jB = j + 128;
  const int row2 = tid >> 6;     // staging row for tid<256
  const int nn = tid & 63;

  const bf16x8* b5 = (const bf16x8*)((const char*)ws + WS_B5_OFS);
  const bf16x8* b3 = (const bf16x8*)((const char*)ws + WS_B3_OFS);
  const bf16x8* b2 = (const bf16x8*)((const char*)ws + WS_B2_OFS);
  short* Hw = (short*)((char*)ws + WS_H_OFS);

  for (int i = tid; i < 16 * 392; i += 512) (&sh_ab[0][0])[i] = 0;
  for (int i = tid; i < 16 * 72; i += 512) (&sh_db[0][0])[i] = 0;

  const float tdxw  = td_x_W[nn * NF + nn];
  const float tdxb  = td_x_b[nn];
  const float featb = feat_b[nn];
  const float featd = feat_W[nn * NF + nn];
  const float combb = comb_b[nn];
  float bgA[4], bgB[4];
  #pragma unroll
  for (int q = 0; q < 4; ++q) {
    bgA[q] = b_ih[q * 256 + jA] + b_hh[q * 256 + jA];
    bgB[q] = b_ih[q * 256 + jB] + b_hh[q * 256 + jB];
  }
  float thb[2];
  thb[0] = td_h_b[(wv * 2 + 0) * 16 + lm];
  thb[1] = td_h_b[(wv * 2 + 1) * 16 + lm];
  float hbv = 0.f;
  if (wv < 4) hbv = hist_b[wv * 16 + lm];

  float cA = 0.f, cB = 0.f;
  double lossAcc = 0.0;

  // ---- pre-loop: stage t=0 inputs, gamma_x(0), d_1 -> sh_db, msum(0)
  float pv_x = 0.f, pv_m = 0.f, pv_d2 = 0.f, pv_msum = 0.f;
  if (tid < 256) {
    size_t g = (size_t)(b0 + row2) * (SS * NF) + nn;
    sh_x[row2][nn] = values[g];
    float d0 = deltas[g];
    sh_gx[row2][nn] = expf(-fmaxf(d0 * tdxw + tdxb, 0.f));
    float d1 = deltas[g + NF];           // SS >= 2
    sh_db[row2][nn] = f2bs(d1);
    pv_d2 = d1;                           // becomes pv_d1 at A(0)
  } else {
    int q = tid - 256; int rw = q >> 6, n2 = q & 63;
    size_t g = (size_t)(b0 + rw) * (SS * NF) + n2;
    float mv = masks_g[g];
    sh_m[rw][n2] = mv;
    sh_ab[rw][64 + n2] = f2bs(mv);
  }
  if (tid == 0) sh_msum = ws[16];
  __syncthreads();

  for (int t = 0; t < SS; ++t) {
    // ================= Segment A =================
    // prefetch-issue for t+1 (x,m,msum) and t+2 (d)
    float pv_d1 = pv_d2;
    if (t + 1 < SS) {
      if (tid < 256) {
        size_t g = (size_t)(b0 + row2) * (SS * NF) + (size_t)(t + 1) * NF + nn;
        pv_x = values[g];
        if (t + 2 < SS) pv_d2 = deltas[g + NF];
      } else {
        int q = tid - 256; int rw = q >> 6, n2 = q & 63;
        size_t g = (size_t)(b0 + rw) * (SS * NF) + (size_t)(t + 1) * NF + n2;
        pv_m = masks_g[g];
      }
      if (tid == 0) pv_msum = ws[16 + t + 1];
    }

    // gates partial: [m|h_dec] @ W^T over kt 2..11 (640KB of b5).
    // A-frags (10) reused across all 8 n-tiles of this wave.
    {
      bf16x8 hm[10];
      #pragma unroll
      for (int q = 0; q < 10; ++q)
        hm[q] = *(const bf16x8*)(&sh_ab[lm][64] + q * 32 + lq * 8);
      #pragma unroll 2
      for (int ntl = 0; ntl < 8; ++ntl) {
        int nt = wv * 8 + ntl;
        f32x4 acc = {0.f, 0.f, 0.f, 0.f};
        const bf16x8* bp = b5 + ((size_t)(nt * 12) + 2) * 64 + lane;
        #pragma unroll
        for (int q = 0; q < 10; ++q)
          acc = __builtin_amdgcn_mfma_f32_16x16x32_bf16(hm[q], bp[q * 64], acc, 0, 0, 0);
        if (lq == 0) {
          int n = nt * 16 + lm;
          #pragma unroll
          for (int r = 0; r < 4; ++r) sh_gates[r][n] = acc[r];
        }
      }
    }

    // gamma_h(t+1) MFMA from sh_db (= d_{t+1}); all 8 waves, 2 tiles each
    {
      bf16x8 dfr[2];
      #pragma unroll
      for (int kt = 0; kt < 2; ++kt)
        dfr[kt] = *(const bf16x8*)(&sh_db[lm][0] + kt * 32 + lq * 8);
      #pragma unroll
      for (int ntl = 0; ntl < 2; ++ntl) {
        int nt = wv * 2 + ntl;
        f32x4 acc = {0.f, 0.f, 0.f, 0.f};
        const bf16x8* bp = b2 + (size_t)(nt * 2) * 64 + lane;
        acc = __builtin_amdgcn_mfma_f32_16x16x32_bf16(dfr[0], bp[0], acc, 0, 0, 0);
        acc = __builtin_amdgcn_mfma_f32_16x16x32_bf16(dfr[1], bp[64], acc, 0, 0, 0);
        if (lq == 0) {
          int g = nt * 16 + lm;
          float bias = thb[ntl];
          #pragma unroll
          for (int r = 0; r < 4; ++r)
            sh_gam[r][g] = expf(-fmaxf(acc[r] + bias, 0.f));
        }
      }
    }

    // x_h = h_dec @ hist^T (waves 0-3); writers: xh, xc, loss
    if (wv < 4) {
      int nt = wv;
      f32x4 acc = {0.f, 0.f, 0.f, 0.f};
      const bf16x8* bp = b3 + (size_t)(nt * 8) * 64 + lane;
      #pragma unroll
      for (int kt = 0; kt < 8; ++kt) {
        bf16x8 a = *(const bf16x8*)(&sh_ab[lm][128] + kt * 32 + lq * 8);
        acc = __builtin_amdgcn_mfma_f32_16x16x32_bf16(a, bp[kt * 64], acc, 0, 0, 0);
      }
      if (lq == 0) {
        int n = nt * 16 + lm;
        float lterm = 0.f;
        #pragma unroll
        for (int r = 0; r < 4; ++r) {
          float xh = acc[r] + hbv;
          sh_xh[r][n] = xh;
          float m = sh_m[r][n], x = sh_x[r][n];
          sh_xc[r][n] = m * x + (1.f - m) * xh;
          lterm += fabsf(x - xh) * m;
        }
        lossAcc += (double)(lterm / sh_msum);
      }
    }
    __syncthreads(); // SA

    // ================= Segment B =================
    if (tid < 256) {
      const float4* xc4 = (const float4*)&sh_xc[row2][0];
      const float4* gx4 = (const float4*)&sh_gx[row2][0];
      const float4* mm4 = (const float4*)&sh_m[row2][0];
      const float4* fW  = (const float4*)(feat_W + nn * NF);
      const float4* cW0 = (const float4*)(comb_W + nn * 2 * NF);
      const float4* cW1 = (const float4*)(comb_W + nn * 2 * NF + NF);
      float az = 0.f, aa = 0.f;
      #pragma unroll
      for (int k = 0; k < 16; ++k) {
        az += dot4f(xc4[k], fW[k]);
        aa += dot4f(gx4[k], cW0[k]);
        aa += dot4f(mm4[k], cW1[k]);
      }
      float xcn = sh_xc[row2][nn];
      float zh = az - xcn * featd + featb;
      float alpha = aa + combb;
      float xh = sh_xh[row2][nn];
      float chv = alpha * zh + (1.f - alpha) * xh;
      float m = sh_m[row2][nn], x = sh_x[row2][nn];
      float ccv = m * x + (1.f - m) * chv;
      sh_ab[row2][nn] = f2bs(ccv);
      out[1 + BB + ((size_t)(b0 + row2) * SS + t) * NF + nn] = ccv;
      float lsum = (fabsf(x - zh) + fabsf(x - chv)) * m;
      lossAcc += (double)(lsum / sh_msum);
    }
    __syncthreads(); // SB

    // ================= Segment C (c_c part of gates: kt 0..1) =============
    {
      bf16x8 ccf[2];
      #pragma unroll
      for (int kt = 0; kt < 2; ++kt)
        ccf[kt] = *(const bf16x8*)(&sh_ab[lm][0] + kt * 32 + lq * 8);
      #pragma unroll
      for (int ntl = 0; ntl < 8; ++ntl) {
        int nt = wv * 8 + ntl;
        f32x4 acc = {0.f, 0.f, 0.f, 0.f};
        const bf16x8* bp = b5 + (size_t)(nt * 12) * 64 + lane;
        acc = __builtin_amdgcn_mfma_f32_16x16x32_bf16(ccf[0], bp[0], acc, 0, 0, 0);
        acc = __builtin_amdgcn_mfma_f32_16x16x32_bf16(ccf[1], bp[64], acc, 0, 0, 0);
        if (lq == 0) {
          int n = nt * 16 + lm;
          #pragma unroll
          for (int r = 0; r < 4; ++r) sh_gates[r][n] += acc[r];
        }
      }
    }
    __syncthreads(); // SC

    // ================= Segment D =================
    // LSTM update, decay with gamma_h(t+1), H write, stage t+1 inputs
    {
      float giA = sh_gates[row][jA] + bgA[0];
      float gfA = sh_gates[row][256 + jA] + bgA[1];
      float ggA = sh_gates[row][512 + jA] + bgA[2];
      float goA = sh_gates[row][768 + jA] + bgA[3];
      float iA = 1.f / (1.f + expf(-giA));
      float fA = 1.f / (1.f + expf(-gfA));
      float oA = 1.f / (1.f + expf(-goA));
      cA = fA * cA + iA * tanhf(ggA);
      float hnA = oA * tanhf(cA);
      float giB = sh_gates[row][jB] + bgB[0];
      float gfB = sh_gates[row][256 + jB] + bgB[1];
      float ggB = sh_gates[row][512 + jB] + bgB[2];
      float goB = sh_gates[row][768 + jB] + bgB[3];
      float iB = 1.f / (1.f + expf(-giB));
      float fB = 1.f / (1.f + expf(-gfB));
      float oB = 1.f / (1.f + expf(-goB));
      cB = fB * cB + iB * tanhf(ggB);
      float hnB = oB * tanhf(cB);
      // H buffer gets the UNdecayed h
      size_t hb = ((size_t)(b0 + row) * SS + t) * HD;
      Hw[hb + jA] = f2bs(hnA);
      Hw[hb + jB] = f2bs(hnB);
      // decayed h for next step's x_h/gates
      float hdA = hnA * sh_gam[row][jA];
      float hdB = hnB * sh_gam[row][jB];
      sh_ab[row][128 + jA] = f2bs(hdA);
      sh_ab[row][128 + jB] = f2bs(hdB);
    }
    if (t + 1 < SS) {
      if (tid < 256) {
        sh_x[row2][nn] = pv_x;
        sh_gx[row2][nn] = expf(-fmaxf(pv_d1 * tdxw + tdxb, 0.f)); // gamma_x(t+1)
        sh_db[row2][nn] = f2bs(pv_d2);                            // d_{t+2}
      } else {
        int q = tid - 256; int rw = q >> 6, n2 = q & 63;
        sh_m[rw][n2] = pv_m;
        sh_ab[rw][64 + n2] = f2bs(pv_m);
      }
      if (tid == 0) sh_msum = pv_msum;
    }
    __syncthreads(); // SD
  }

  // loss reduce (x_loss only)
  float* sred = &sh_gates[0][0];
  sred[tid] = (float)lossAcc;
  __syncthreads();
  for (int off = 256; off > 0; off >>= 1) {
    if (tid < off) sred[tid] += sred[tid + off];
    __syncthreads();
  }
  if (tid == 0) atomicAdd(&ws[0], sred[0]);
}

// ---------------- attention kernel: one block per batch row ----------------
__global__ __launch_bounds__(256) void rits_attn(
    const float* __restrict__ labels, const float* __restrict__ is_train,
    const float* __restrict__ Ws1_b,
    const float* __restrict__ out_W, const float* __restrict__ out_b,
    float* __restrict__ out, float* __restrict__ ws)
{
  __shared__ __align__(16) short sh_s1[16][360];  // bf16 s1 chunk, cols>=350 zero
  __shared__ __align__(16) float sh_sc[32][256];  // scoresT [r][s] f32
  __shared__ __align__(16) short sh_at[32][264];  // attn bf16 [r][s], rows 30,31 zero

  const int tid = threadIdx.x;
  const int b = blockIdx.x;
  const int wv = tid >> 6;       // wave 0..3
  const int lane = tid & 63;
  const int lm = lane & 15;
  const int lq = lane >> 4;

  const bf16x8* b6 = (const bf16x8*)((const char*)ws + WS_B6_OFS);
  const bf16x8* b7 = (const bf16x8*)((const char*)ws + WS_B7_OFS);
  const ushort* Hg = (const ushort*)((const char*)ws + WS_H_OFS) + (size_t)b * SS * HD;

  for (int i = tid; i < 16 * 360; i += 256) (&sh_s1[0][0])[i] = 0;
  for (int i = tid; i < 32 * 264; i += 256) (&sh_at[0][0])[i] = 0;

  float w1b[6];
  #pragma unroll
  for (int i = 0; i < 6; ++i) {
    int nt = wv + 4 * i;
    int a = nt * 16 + lm;
    w1b[i] = (nt < 22 && a < DAA) ? Ws1_b[a] : 0.f;
  }
  __syncthreads();

  for (int sc0 = 0; sc0 < SS; sc0 += 16) {
    bf16x8 afr[8];
    const ushort* Hrow = Hg + (size_t)(sc0 + lm) * HD;
    #pragma unroll
    for (int kt = 0; kt < 8; ++kt)
      afr[kt] = *(const bf16x8*)(Hrow + kt * 32 + lq * 8);
    int i = 0;
    for (int nt = wv; nt < 22; nt += 4, ++i) {
      f32x4 acc = {0.f, 0.f, 0.f, 0.f};
      const bf16x8* bp = b6 + (size_t)(nt * 8) * 64 + lane;
      #pragma unroll
      for (int kt = 0; kt < 8; ++kt)
        acc = __builtin_amdgcn_mfma_f32_16x16x32_bf16(afr[kt], bp[kt * 64], acc, 0, 0, 0);
      int a = nt * 16 + lm;
      if (a < DAA) {
        float bias = w1b[i];
        #pragma unroll
        for (int r = 0; r < 4; ++r)
          sh_s1[lq * 4 + r][a] = f2bs(tanhf(acc[r] + bias));
      }
    }
    __syncthreads();
    if (wv < 2) {
      bf16x8 s1f[11];
      #pragma unroll
      for (int kt = 0; kt < 11; ++kt)
        s1f[kt] = *(const bf16x8*)(&sh_s1[lm][0] + kt * 32 + lq * 8);
      f32x4 acc = {0.f, 0.f, 0.f, 0.f};
      const bf16x8* bp = b7 + (size_t)(wv * 11) * 64 + lane;
      #pragma unroll
      for (int kt = 0; kt < 11; ++kt)
        acc = __builtin_amdgcn_mfma_f32_16x16x32_bf16(s1f[kt], bp[kt * 64], acc, 0, 0, 0);
      int r = wv * 16 + lm;
      if (r < DRR) {
        float4 v = {acc[0], acc[1], acc[2], acc[3]};
        *(float4*)&sh_sc[r][sc0 + lq * 4] = v;
      }
    }
    __syncthreads();
  }

  if (tid < 240) {
    int r = tid >> 3, g = tid & 7;
    float M = -1e30f;
    for (int s = g; s < SS; s += 8) M = fmaxf(M, sh_sc[r][s]);
    #pragma unroll
    for (int off = 1; off < 8; off <<= 1) M = fmaxf(M, __shfl_xor(M, off));
    float L = 0.f;
    for (int s = g; s < SS; s += 8) {
      float e = expf(sh_sc[r][s] - M);
      sh_sc[r][s] = e;
      L += e;
    }
    #pragma unroll
    for (int off = 1; off < 8; off <<= 1) L += __shfl_xor(L, off);
    float inv = 1.f / L;
    for (int s = g; s < SS; s += 8) sh_at[r][s] = f2bs(sh_sc[r][s] * inv);
  }
  __syncthreads();

  bf16x8 aat[2][8];
  #pragma unroll
  for (int mt = 0; mt < 2; ++mt)
    #pragma unroll
    for (int kt = 0; kt < 8; ++kt)
      aat[mt][kt] = *(const bf16x8*)(&sh_at[mt * 16 + lm][0] + kt * 32 + lq * 8);

  float p = 0.f;
  #pragma unroll
  for (int ntl = 0; ntl < 4; ++ntl) {
    int nt = wv * 4 + ntl;
    f32x4 acc0 = {0.f, 0.f, 0.f, 0.f};
    f32x4 acc1 = {0.f, 0.f, 0.f, 0.f};
    #pragma unroll
    for (int kt = 0; kt < 8; ++kt) {
      const ushort* hp = Hg + (size_t)(kt * 32 + lq * 8) * HD + nt * 16 + lm;
      bf16x8 bf;
      #pragma unroll
      for (int jj = 0; jj < 8; ++jj) bf[jj] = (short)hp[(size_t)jj * HD];
      acc0 = __builtin_amdgcn_mfma_f32_16x16x32_bf16(aat[0][kt], bf, acc0, 0, 0, 0);
      acc1 = __builtin_amdgcn_mfma_f32_16x16x32_bf16(aat[1][kt], bf, acc1, 0, 0, 0);
    }
    int h = nt * 16 + lm;
    #pragma unroll
    for (int ri = 0; ri < 4; ++ri) {
      int r0 = lq * 4 + ri;
      p += out_W[r0 * HD + h] * acc0[ri];
      int r1 = 16 + lq * 4 + ri;
      if (r1 < DRR) p += out_W[r1 * HD + h] * acc1[ri];
    }
  }

  float* sred = &sh_sc[0][0];
  __syncthreads();
  sred[tid] = p;
  __syncthreads();
  for (int off = 128; off > 0; off >>= 1) {
    if (tid < off) sred[tid] += sred[tid + off];
    __syncthreads();
  }
  if (tid == 0) {
    float yh = sred[0] + out_b[0];
    float lab = labels[b], tr = is_train[b];
    float bce = fmaxf(yh, 0.f) - yh * lab + log1pf(expf(-fabsf(yh)));
    atomicAdd(&ws[1], bce * tr);
    out[1 + b] = 1.f / (1.f + expf(-yh));
  }
}

// ---------------- fused fallback (verbatim round-0 kernel, 6179us) ---------
__global__ __launch_bounds__(512, 2) void rits_fused(
    const float* __restrict__ values, const float* __restrict__ masks_g,
    const float* __restrict__ deltas, const float* __restrict__ labels,
    const float* __restrict__ is_train,
    const float* __restrict__ td_h_b, const float* __restrict__ td_x_W,
    const float* __restrict__ td_x_b, const float* __restrict__ hist_b,
    const float* __restrict__ feat_W, const float* __restrict__ feat_b,
    const float* __restrict__ comb_W, const float* __restrict__ comb_b,
    const float* __restrict__ b_ih, const float* __restrict__ b_hh,
    const float* __restrict__ Ws1_b,
    const float* __restrict__ Ws2_W, const float* __restrict__ Ws2_b,
    const float* __restrict__ out_W, const float* __restrict__ out_b,
    float* __restrict__ out, float* __restrict__ ws)
{
  __shared__ __align__(16) float sh_a[4][384];
  __shared__ __align__(16) short sh_ab[16][392];
  __shared__ __align__(16) short sh_db[16][72];
  __shared__ __align__(16) float sh_x[4][NF];
  __shared__ __align__(16) float sh_d[4][NF];
  __shared__ __align__(16) float sh_xc[4][NF];
  __shared__ __align__(16) float sh_gx[4][NF];
  __shared__ __align__(16) float sh_xh[4][NF];
  __shared__ __align__(16) float sh_gates[4][1024];
  __shared__ __align__(16) float sh_s1[4][352];
  __shared__ float sh_w[4][32];
  __shared__ float sh_scale[4][32];
  __shared__ float sh_M[4][32];
  __shared__ float sh_L[4][32];
  __shared__ float sh_msum;

  const int tid = threadIdx.x;
  const int b0 = blockIdx.x * 4;
  const int wv = tid >> 6;
  const int lane = tid & 63;
  const int lm = lane & 15;
  const int lq = lane >> 4;
  const int row = tid >> 7;
  const int j = tid & 127;
  const int jA = j, jB = j + 128;
  const int row2 = tid >> 6;
  const int nn = tid & 63;

  const bf16x8* b5 = (const bf16x8*)((const char*)ws + WS_B5_OFS);
  const bf16x8* b6 = (const bf16x8*)((const char*)ws + WS_B6_OFS);
  const bf16x8* b3 = (const bf16x8*)((const char*)ws + WS_B3_OFS);
  const bf16x8* b2 = (const bf16x8*)((const char*)ws + WS_B2_OFS);

  for (int i = tid; i < 16 * 392; i += 512) (&sh_ab[0][0])[i] = 0;
  for (int i = tid; i < 16 * 72; i += 512) (&sh_db[0][0])[i] = 0;
  for (int i = tid; i < 4 * 384; i += 512) (&sh_a[0][0])[i] = 0.f;
  if (tid < 128) {
    int rr = tid >> 5, q = tid & 31;
    sh_M[rr][q] = -1e30f;
    sh_L[rr][q] = 0.f;
  }

  const float tdxw  = td_x_W[nn * NF + nn];
  const float tdxb  = td_x_b[nn];
  const float featb = feat_b[nn];
  const float featd = feat_W[nn * NF + nn];
  const float combb = comb_b[nn];
  float bgA[4], bgB[4];
  #pragma unroll
  for (int q = 0; q < 4; ++q) {
    bgA[q] = b_ih[q * 256 + jA] + b_hh[q * 256 + jA];
    bgB[q] = b_ih[q * 256 + jB] + b_hh[q * 256 + jB];
  }

  float cA = 0.f, cB = 0.f;
  float OA[DRR], OBv[DRR];
  #pragma unroll
  for (int r = 0; r < DRR; ++r) { OA[r] = 0.f; OBv[r] = 0.f; }
  double lossAcc = 0.0;

  __syncthreads();

  for (int t = 0; t < SS; ++t) {
    if (tid < 256) {
      size_t g = (size_t)(b0 + row2) * (SS * NF) + (size_t)t * NF + nn;
      float xv = values[g], dv = deltas[g];
      sh_x[row2][nn] = xv;
      sh_d[row2][nn] = dv;
      sh_db[row2][nn] = f2bs(dv);
    } else {
      int q = tid - 256;
      int rw = q >> 6, n2 = q & 63;
      size_t g = (size_t)(b0 + rw) * (SS * NF) + (size_t)t * NF + n2;
      float mv = masks_g[g];
      sh_a[rw][64 + n2] = mv;
      sh_ab[rw][64 + n2] = f2bs(mv);
    }
    if (tid == 0) sh_msum = ws[16 + t];
    __syncthreads();

    {
      bf16x8 dfr[2];
      #pragma unroll
      for (int kt = 0; kt < 2; ++kt)
        dfr[kt] = *(const bf16x8*)(&sh_db[lm][0] + kt * 32 + lq * 8);
      #pragma unroll
      for (int ntl = 0; ntl < 2; ++ntl) {
        int nt = wv * 2 + ntl;
        f32x4 acc = {0.f, 0.f, 0.f, 0.f};
        const bf16x8* bp = b2 + (size_t)(nt * 2) * 64 + lane;
        acc = __builtin_amdgcn_mfma_f32_16x16x32_bf16(dfr[0], bp[0], acc, 0, 0, 0);
        acc = __builtin_amdgcn_mfma_f32_16x16x32_bf16(dfr[1], bp[64], acc, 0, 0, 0);
        if (lq == 0) {
          int g = nt * 16 + lm;
          float bias = td_h_b[g];
          #pragma unroll
          for (int r = 0; r < 4; ++r) {
            float gam = expf(-fmaxf(acc[r] + bias, 0.f));
            float h = sh_a[r][128 + g] * gam;
            sh_a[r][128 + g] = h;
            sh_ab[r][128 + g] = f2bs(h);
          }
        }
      }
      if (tid < 256) {
        float v = sh_d[row2][nn] * tdxw + tdxb;
        sh_gx[row2][nn] = expf(-fmaxf(v, 0.f));
      }
    }
    __syncthreads();

    if (wv < 4) {
      int nt = wv;
      f32x4 acc = {0.f, 0.f, 0.f, 0.f};
      const bf16x8* bp = b3 + (size_t)(nt * 8) * 64 + lane;
      #pragma unroll
      for (int kt = 0; kt < 8; ++kt) {
        bf16x8 a = *(const bf16x8*)(&sh_ab[lm][128] + kt * 32 + lq * 8);
        acc = __builtin_amdgcn_mfma_f32_16x16x32_bf16(a, bp[kt * 64], acc, 0, 0, 0);
      }
      if (lq == 0) {
        int n = nt * 16 + lm;
        float bias = hist_b[n];
        float lterm = 0.f;
        #pragma unroll
        for (int r = 0; r < 4; ++r) {
          float xh = acc[r] + bias;
          sh_xh[r][n] = xh;
          float m = sh_a[r][64 + n], x = sh_x[r][n];
          sh_xc[r][n] = m * x + (1.f - m) * xh;
          lterm += fabsf(x - xh) * m;
        }
        lossAcc += (double)(lterm / sh_msum);
      }
    }
    __syncthreads();

    if (tid < 256) {
      const float4* xc4 = (const float4*)&sh_xc[row2][0];
      const float4* gx4 = (const float4*)&sh_gx[row2][0];
      const float4* mm4 = (const float4*)&sh_a[row2][64];
      const float4* fW  = (const float4*)(feat_W + nn * NF);
      const float4* cW0 = (const float4*)(comb_W + nn * 2 * NF);
      const float4* cW1 = (const float4*)(comb_W + nn * 2 * NF + NF);
      float az = 0.f, aa = 0.f;
      #pragma unroll
      for (int k = 0; k < 16; ++k) {
        az += dot4f(xc4[k], fW[k]);
        aa += dot4f(gx4[k], cW0[k]);
        aa += dot4f(mm4[k], cW1[k]);
      }
      float xcn = sh_xc[row2][nn];
      float zh = az - xcn * featd + featb;
      float alpha = aa + combb;
      float xh = sh_xh[row2][nn];
      float chv = alpha * zh + (1.f - alpha) * xh;
      float m = sh_a[row2][64 + nn], x = sh_x[row2][nn];
      float ccv = m * x + (1.f - m) * chv;
      sh_ab[row2][nn] = f2bs(ccv);
      out[1 + BB + ((size_t)(b0 + row2) * SS + t) * NF + nn] = ccv;
      float lsum = (fabsf(x - zh) + fabsf(x - chv)) * m;
      lossAcc += (double)(lsum / sh_msum);
    }
    __syncthreads();

    {
      bf16x8 afr[12];
      #pragma unroll
      for (int kt = 0; kt < 12; ++kt)
        afr[kt] = *(const bf16x8*)(&sh_ab[lm][0] + kt * 32 + lq * 8);
      #pragma unroll 2
      for (int ntl = 0; ntl < 8; ++ntl) {
        int nt = wv * 8 + ntl;
        f32x4 acc = {0.f, 0.f, 0.f, 0.f};
        const bf16x8* bp = b5 + (size_t)(nt * 12) * 64 + lane;
        #pragma unroll
        for (int kt = 0; kt < 12; ++kt)
          acc = __builtin_amdgcn_mfma_f32_16x16x32_bf16(afr[kt], bp[kt * 64], acc, 0, 0, 0);
        if (lq == 0) {
          int n = nt * 16 + lm;
          #pragma unroll
          for (int r = 0; r < 4; ++r) sh_gates[r][n] = acc[r];
        }
      }
    }
    __syncthreads();

    float hnA, hnB;
    {
      float giA = sh_gates[row][jA] + bgA[0];
      float gfA = sh_gates[row][256 + jA] + bgA[1];
      float ggA = sh_gates[row][512 + jA] + bgA[2];
      float goA = sh_gates[row][768 + jA] + bgA[3];
      float iA = 1.f / (1.f + expf(-giA));
      float fA = 1.f / (1.f + expf(-gfA));
      float oA = 1.f / (1.f + expf(-goA));
      cA = fA * cA + iA * tanhf(ggA);
      hnA = oA * tanhf(cA);
      float giB = sh_gates[row][jB] + bgB[0];
      float gfB = sh_gates[row][256 + jB] + bgB[1];
      float ggB = sh_gates[row][512 + jB] + bgB[2];
      float goB = sh_gates[row][768 + jB] + bgB[3];
      float iB = 1.f / (1.f + expf(-giB));
      float fB = 1.f / (1.f + expf(-gfB));
      float oB = 1.f / (1.f + expf(-goB));
      cB = fB * cB + iB * tanhf(ggB);
      hnB = oB * tanhf(cB);
      sh_a[row][128 + jA] = hnA;
      sh_a[row][128 + jB] = hnB;
      sh_ab[row][128 + jA] = f2bs(hnA);
      sh_ab[row][128 + jB] = f2bs(hnB);
    }
    __syncthreads();

    {
      bf16x8 hfr[8];
      #pragma unroll
      for (int kt = 0; kt < 8; ++kt)
        hfr[kt] = *(const bf16x8*)(&sh_ab[lm][128] + kt * 32 + lq * 8);
      for (int nt = wv; nt < 22; nt += 8) {
        f32x4 acc = {0.f, 0.f, 0.f, 0.f};
        const bf16x8* bp = b6 + (size_t)(nt * 8) * 64 + lane;
        #pragma unroll
        for (int kt = 0; kt < 8; ++kt)
          acc = __builtin_amdgcn_mfma_f32_16x16x32_bf16(hfr[kt], bp[kt * 64], acc, 0, 0, 0);
        if (lq == 0) {
          int a = nt * 16 + lm;
          if (a < DAA) {
            float bias = Ws1_b[a];
            #pragma unroll
            for (int r = 0; r < 4; ++r) sh_s1[r][a] = tanhf(acc[r] + bias);
          }
        }
      }
    }
    __syncthreads();

    if (tid < 4 * DRR) {
      int rw = tid / DRR;
      int r = tid - rw * DRR;
      const float2* s2 = (const float2*)&sh_s1[rw][0];
      const float2* w2 = (const float2*)(Ws2_W + (size_t)r * DAA);
      float acc = 0.f;
      #pragma unroll 5
      for (int k = 0; k < 175; ++k) {
        float2 a = s2[k], b = w2[k];
        acc = fmaf(a.x, b.x, fmaf(a.y, b.y, acc));
      }
      float sc = acc + Ws2_b[r];
      float Mo = sh_M[rw][r];
      float Mn = fmaxf(Mo, sc);
      float scl = expf(Mo - Mn);
      float w = expf(sc - Mn);
      sh_M[rw][r] = Mn;
      sh_L[rw][r] = sh_L[rw][r] * scl + w;
      sh_scale[rw][r] = scl;
      sh_w[rw][r] = w;
    }
    __syncthreads();

    #pragma unroll
    for (int r = 0; r < DRR; ++r) {
      float scl = sh_scale[row][r];
      float w = sh_w[row][r];
      OA[r]  = OA[r]  * scl + w * hnA;
      OBv[r] = OBv[r] * scl + w * hnB;
    }
  }

  float pA = 0.f, pB = 0.f;
  #pragma unroll
  for (int r = 0; r < DRR; ++r) {
    float invL = 1.f / sh_L[row][r];
    pA += out_W[r * HD + jA] * (OA[r]  * invL);
    pB += out_W[r * HD + jB] * (OBv[r] * invL);
  }
  float* sred = &sh_s1[0][0];
  __syncthreads();
  sred[row * 256 + jA] = pA;
  sred[row * 256 + jB] = pB;
  __syncthreads();
  if (tid < 4) {
    float acc = 0.f;
    for (int k = 0; k < 256; ++k) acc += sred[tid * 256 + k];
    float yh = acc + out_b[0];
    int b = b0 + tid;
    float lab = labels[b], tr = is_train[b];
    float bce = fmaxf(yh, 0.f) - yh * lab + log1pf(expf(-fabsf(yh)));
    atomicAdd(&ws[1], bce * tr);
    out[1 + b] = 1.f / (1.f + expf(-yh));
  }
  __syncthreads();
  sred[tid] = (float)lossAcc;
  __syncthreads();
  for (int off = 256; off > 0; off >>= 1) {
    if (tid < off) sred[tid] += sred[tid + off];
    __syncthreads();
  }
  if (tid == 0) atomicAdd(&ws[0], sred[0]);
}

__global__ void final_kernel(const float* __restrict__ ws, float* __restrict__ out) {
  if (threadIdx.x == 0 && blockIdx.x == 0) {
    out[0] = ws[0] / (float)SS + 0.1f * (ws[1] / (ws[2] + 1e-5f));
  }
}

extern "C" void kernel_launch(void* const* d_in, const int* in_sizes, int n_in,
                              void* d_out, int out_size, void* d_ws, size_t ws_size,
                              hipStream_t stream) {
  const float* values   = (const float*)d_in[0];
  const float* masks    = (const float*)d_in[1];
  const float* deltas   = (const float*)d_in[2];
  const float* labels   = (const float*)d_in[3];
  const float* is_train = (const float*)d_in[4];
  const float* td_h_W   = (const float*)d_in[5];
  const float* td_h_b   = (const float*)d_in[6];
  const float* td_x_W   = (const float*)d_in[7];
  const float* td_x_b   = (const float*)d_in[8];
  const float* hist_W   = (const float*)d_in[9];
  const float* hist_b   = (const float*)d_in[10];
  const float* feat_W   = (const float*)d_in[11];
  const float* feat_b   = (const float*)d_in[12];
  const float* comb_W   = (const float*)d_in[13];
  const float* comb_b   = (const float*)d_in[14];
  const float* W_ih     = (const float*)d_in[15];
  const float* b_ih     = (const float*)d_in[16];
  const float* W_hh     = (const float*)d_in[17];
  const float* b_hh     = (const float*)d_in[18];
  const float* Ws1_W    = (const float*)d_in[19];
  const float* Ws1_b    = (const float*)d_in[20];
  const float* Ws2_W    = (const float*)d_in[21];
  const float* Ws2_b    = (const float*)d_in[22];
  const float* out_W    = (const float*)d_in[23];
  const float* out_b    = (const float*)d_in[24];
  float* out = (float*)d_out;
  float* ws  = (float*)d_ws;

  short* b5 = (short*)((char*)d_ws + WS_B5_OFS);
  short* b6 = (short*)((char*)d_ws + WS_B6_OFS);
  short* b3 = (short*)((char*)d_ws + WS_B3_OFS);
  short* b2 = (short*)((char*)d_ws + WS_B2_OFS);
  short* b7 = (short*)((char*)d_ws + WS_B7_OFS);

  convert_weights<<<(CW_TOTAL + 255) / 256, 256, 0, stream>>>(
      W_ih, W_hh, Ws1_W, hist_W, td_h_W, Ws2_W, b5, b6, b3, b2, b7);
  prep_kernel<<<SS, 256, 0, stream>>>(masks, is_train, ws);

  if (ws_size >= (size_t)WS_H_OFS + WS_H_BYTES) {
    rits_scan<<<BB / RPB, 512, 0, stream>>>(
        values, masks, deltas,
        td_h_b, td_x_W, td_x_b, hist_b, feat_W, feat_b, comb_W, comb_b,
        b_ih, b_hh, out, ws);
    rits_attn<<<BB, 256, 0, stream>>>(
        labels, is_train, Ws1_b, out_W, out_b, out, ws);
  } else {
    rits_fused<<<BB / 4, 512, 0, stream>>>(
        values, masks, deltas, labels, is_train,
        td_h_b, td_x_W, td_x_b, hist_b, feat_W, feat_b, comb_W, comb_b,
        b_ih, b_hh, Ws1_b, Ws2_W, Ws2_b, out_W, out_b, out, ws);
  }
  final_kernel<<<1, 64, 0, stream>>>(ws, out);
}